// Round 1
// baseline (426.002 us; speedup 1.0000x reference)
//
#include <hip/hip_runtime.h>

// ---------------------------------------------------------------------------
// SeqPairAttentionOutput on MI355X — full pipeline, bf16 MFMA GEMMs.
// B=1, L=512, D=1024, H=16, HW=64, PD=128.
// ---------------------------------------------------------------------------

typedef __attribute__((ext_vector_type(8))) short bfrag;   // 8 bf16 (4 VGPRs)
typedef __attribute__((ext_vector_type(4))) float f32x4;

#define LL 512
#define DD 1024
#define NHEAD 16
#define HDIM 64
#define PDIM 128

__device__ __forceinline__ unsigned short f2b(float x) {
  union { float f; unsigned u; } a; a.f = x;
  unsigned r = a.u + 0x7fffu + ((a.u >> 16) & 1u);   // RNE
  return (unsigned short)(r >> 16);
}
__device__ __forceinline__ unsigned pack2(float a, float b) {
  return (unsigned)f2b(a) | ((unsigned)f2b(b) << 16);
}

// ---------------------------------------------------------------------------
// workspace layout (bytes)
// ---------------------------------------------------------------------------
#define OFF_GW    ((size_t)0)                       // gw[16][128], c1[16], c2[16] fp32
#define OFF_BIAS  ((size_t)65536)                   // bias then scores S, [16][512][512] f32
#define OFF_P     (OFF_BIAS  + (size_t)16777216)    // P bf16 [16][512][512]
#define OFF_Y     (OFF_P     + (size_t)8388608)     // y bf16 [512][1024]
#define OFF_T     (OFF_Y     + (size_t)1048576)     // t f32 [512][3072]
#define OFF_GATE  (OFF_T     + (size_t)6291456)     // gate f32 [512][1024]
#define OFF_QS    (OFF_GATE  + (size_t)2097152)     // q bf16 [16][512][64] (scaled)
#define OFF_KS    (OFF_QS    + (size_t)1048576)     // k bf16 [16][512][64]
#define OFF_VT    (OFF_KS    + (size_t)1048576)     // v^T bf16 [16][64][512]
#define OFF_O     (OFF_VT    + (size_t)1048576)     // o f32 [512][1024]
#define OFF_OG    (OFF_O     + (size_t)2097152)     // gate*o bf16 [512][1024]
#define OFF_S     (OFF_OG    + (size_t)1048576)     // s f32 [512][1024]
#define OFF_HLN   (OFF_S     + (size_t)2097152)     // LN(s) bf16 [512][1024]
#define OFF_H1    (OFF_HLN   + (size_t)1048576)     // h1 bf16 [512][4096]
#define OFF_WPROJ (OFF_H1    + (size_t)4194304)     // proj_w^T bf16 [3072][1024]
#define OFF_WG    (OFF_WPROJ + (size_t)6291456)     // g_w^T bf16 [1024][1024]
#define OFF_WO    (OFF_WG    + (size_t)2097152)     // o_w^T bf16 [1024][1024]
#define OFF_W1    (OFF_WO    + (size_t)2097152)     // w1^T bf16 [4096][1024]
#define OFF_W2    (OFF_W1    + (size_t)8388608)     // w2^T bf16 [1024][4096]

// ---------------------------------------------------------------------------
// p2s setup: gw[h][f] = p2s_ln_g[f] * p2s_w[f][h]; c1[h]=sum_f g*w; c2[h]=sum_f b*w
// ---------------------------------------------------------------------------
__global__ __launch_bounds__(256) void p2s_setup(
    const float* __restrict__ g, const float* __restrict__ b,
    const float* __restrict__ w, float* __restrict__ gw) {
  int t = threadIdx.x;
  for (int i = t; i < 2048; i += 256) {
    int h = i >> 7, f = i & 127;
    gw[h * 128 + f] = g[f] * w[f * 16 + h];
  }
  if (t < 16) {
    float a = 0.f, c = 0.f;
    for (int f = 0; f < 128; f++) { a += g[f] * w[f * 16 + t]; c += b[f] * w[f * 16 + t]; }
    gw[2048 + t] = a;   // c1
    gw[2064 + t] = c;   // c2
  }
}

// ---------------------------------------------------------------------------
// p2s main: per (q,k) pair LN-fold + 16-head projection.
// bias[h][qk] = rs*(dot(x,gw_h) - mu*c1[h]) + c2[h]
// block = 256 threads = 16 pairs x 16 heads.
// ---------------------------------------------------------------------------
__global__ __launch_bounds__(256) void p2s_main(
    const float* __restrict__ pw, const float* __restrict__ gw,
    float* __restrict__ biasOut) {
  __shared__ float xs[16 * 132];
  __shared__ float gwt[16 * 132];
  const int t = threadIdx.x;
  const long pair0 = (long)blockIdx.x * 16;
  const int p = t >> 4;          // pair within block (0..15)
  const int h = t & 15;          // head / feature-chunk (0..15)
  const int f0 = h * 8;

  // stage gw (16x128) and x (16 pairs x 128) into LDS, padded stride 132
  float4 w0 = *(const float4*)&gw[p * 128 + f0];
  float4 w1 = *(const float4*)&gw[p * 128 + f0 + 4];
  *(float4*)&gwt[p * 132 + f0]     = w0;
  *(float4*)&gwt[p * 132 + f0 + 4] = w1;
  const float* src = pw + pair0 * 128 + (long)t * 8;
  float4 x0 = *(const float4*)src;
  float4 x1 = *(const float4*)(src + 4);
  *(float4*)&xs[p * 132 + f0]     = x0;
  *(float4*)&xs[p * 132 + f0 + 4] = x1;

  // stats from registers (this thread loaded features f0..f0+7 of pair p)
  float s  = x0.x + x0.y + x0.z + x0.w + x1.x + x1.y + x1.z + x1.w;
  float sq = x0.x*x0.x + x0.y*x0.y + x0.z*x0.z + x0.w*x0.w
           + x1.x*x1.x + x1.y*x1.y + x1.z*x1.z + x1.w*x1.w;
#pragma unroll
  for (int m = 1; m < 16; m <<= 1) { s += __shfl_xor(s, m); sq += __shfl_xor(sq, m); }
  float mu  = s * (1.f / 128.f);
  float var = sq * (1.f / 128.f) - mu * mu;
  float rs  = rsqrtf(var + 1e-5f);

  __syncthreads();

  float acc = 0.f;
#pragma unroll 8
  for (int f = 0; f < 128; f += 4) {
    float4 xv = *(const float4*)&xs[p * 132 + f];
    float4 wv = *(const float4*)&gwt[h * 132 + f];
    acc += xv.x * wv.x + xv.y * wv.y + xv.z * wv.z + xv.w * wv.w;
  }
  float c1 = gw[2048 + h], c2 = gw[2064 + h];
  biasOut[(long)h * 262144 + pair0 + p] = rs * (acc - mu * c1) + c2;
}

// ---------------------------------------------------------------------------
// transpose + fp32->bf16 convert: W[K][N] -> Wt[N][K]
// grid (N/64, K/64), block 256
// ---------------------------------------------------------------------------
__global__ __launch_bounds__(256) void transpose_cvt(
    const float* __restrict__ W, unsigned short* __restrict__ Wt, int K, int N) {
  __shared__ float tile[64][65];
  int n0 = blockIdx.x * 64, k0 = blockIdx.y * 64;
  int t = threadIdx.x;
  int tr = t >> 4, tc = (t & 15) * 4;
#pragma unroll
  for (int i = 0; i < 4; i++) {
    int r = tr + i * 16;
    float4 v = *(const float4*)&W[(long)(k0 + r) * N + n0 + tc];
    tile[r][tc] = v.x; tile[r][tc + 1] = v.y; tile[r][tc + 2] = v.z; tile[r][tc + 3] = v.w;
  }
  __syncthreads();
  int nr = t >> 2, kk = (t & 3) * 16;
  unsigned short* dst = Wt + (long)(n0 + nr) * K + k0 + kk;
  uint4 q;
  q.x = pack2(tile[kk + 0][nr], tile[kk + 1][nr]);
  q.y = pack2(tile[kk + 2][nr], tile[kk + 3][nr]);
  q.z = pack2(tile[kk + 4][nr], tile[kk + 5][nr]);
  q.w = pack2(tile[kk + 6][nr], tile[kk + 7][nr]);
  *(uint4*)dst = q;
  uint4 q2;
  q2.x = pack2(tile[kk + 8][nr],  tile[kk + 9][nr]);
  q2.y = pack2(tile[kk + 10][nr], tile[kk + 11][nr]);
  q2.z = pack2(tile[kk + 12][nr], tile[kk + 13][nr]);
  q2.w = pack2(tile[kk + 14][nr], tile[kk + 15][nr]);
  *(uint4*)(dst + 8) = q2;
}

// ---------------------------------------------------------------------------
// row LayerNorm (C=1024) -> bf16. block=256 per row.
// ---------------------------------------------------------------------------
__global__ __launch_bounds__(256) void ln_rows(
    const float* __restrict__ x, const float* __restrict__ g,
    const float* __restrict__ b, unsigned short* __restrict__ out) {
  __shared__ float ps[8];
  int row = blockIdx.x, t = threadIdx.x;
  float4 v = *(const float4*)(x + (long)row * 1024 + t * 4);
  float s  = v.x + v.y + v.z + v.w;
  float sq = v.x*v.x + v.y*v.y + v.z*v.z + v.w*v.w;
#pragma unroll
  for (int k = 1; k < 64; k <<= 1) { s += __shfl_xor(s, k); sq += __shfl_xor(sq, k); }
  if ((t & 63) == 0) { ps[t >> 6] = s; ps[4 + (t >> 6)] = sq; }
  __syncthreads();
  s  = ps[0] + ps[1] + ps[2] + ps[3];
  sq = ps[4] + ps[5] + ps[6] + ps[7];
  float mu = s * (1.f / 1024.f);
  float rs = rsqrtf(sq * (1.f / 1024.f) - mu * mu + 1e-5f);
  float4 gv = *(const float4*)(g + t * 4);
  float4 bv = *(const float4*)(b + t * 4);
  uint2 o;
  o.x = pack2((v.x - mu) * rs * gv.x + bv.x, (v.y - mu) * rs * gv.y + bv.y);
  o.y = pack2((v.z - mu) * rs * gv.z + bv.z, (v.w - mu) * rs * gv.w + bv.w);
  *(uint2*)(out + (long)row * 1024 + t * 4) = o;
}

// ---------------------------------------------------------------------------
// generic bf16 MFMA GEMM, B-transposed inputs: D[m][n] = sum_k A[m][k]*Bt[n][k]
// 64x64 tile / block (4 waves, each 16 rows x 64 cols), BK=32.
// EPI: 0=store f32; 1=+bias1,sigmoid,f32; 2=+bias1+resid,f32; 3=+bias1,relu,bf16;
//      4=+bias2[z][m][n], f32
// ---------------------------------------------------------------------------
template <int EPI>
__global__ __launch_bounds__(256) void gemm_bt(
    const unsigned short* __restrict__ A, const unsigned short* __restrict__ Bt,
    const float* __restrict__ bias1, const float* __restrict__ bias2,
    const float* __restrict__ resid, float* __restrict__ outF,
    unsigned short* __restrict__ outH,
    int K, int ldc, long sAz, long sBz, long sCz, long sB2z) {
  __shared__ unsigned short As[64 * 40];   // +8 pad -> <=2-way bank conflicts (free)
  __shared__ unsigned short Bs[64 * 40];
  const int tid = threadIdx.x;
  const int wave = tid >> 6, lane = tid & 63;
  const int srow = tid >> 2;            // staging row 0..63
  const int skcol = (tid & 3) * 8;      // staging k-chunk
  const int m0 = blockIdx.y * 64, n0 = blockIdx.x * 64;
  const int z = blockIdx.z;
  const unsigned short* Az = A + (long)z * sAz + (long)m0 * K;
  const unsigned short* Bz = Bt + (long)z * sBz + (long)n0 * K;
  const int ln = lane & 15, quad = lane >> 4;

  f32x4 acc[4];
#pragma unroll
  for (int i = 0; i < 4; i++) acc[i] = (f32x4){0.f, 0.f, 0.f, 0.f};

  for (int k0 = 0; k0 < K; k0 += 32) {
    uint4 av = *(const uint4*)(Az + (long)srow * K + k0 + skcol);
    uint4 bv = *(const uint4*)(Bz + (long)srow * K + k0 + skcol);
    __syncthreads();
    *(uint4*)&As[srow * 40 + skcol] = av;
    *(uint4*)&Bs[srow * 40 + skcol] = bv;
    __syncthreads();
    bfrag a = *(const bfrag*)&As[(wave * 16 + ln) * 40 + quad * 8];
#pragma unroll
    for (int t4 = 0; t4 < 4; t4++) {
      bfrag b = *(const bfrag*)&Bs[(t4 * 16 + ln) * 40 + quad * 8];
      acc[t4] = __builtin_amdgcn_mfma_f32_16x16x32_bf16(a, b, acc[t4], 0, 0, 0);
    }
  }

#pragma unroll
  for (int t4 = 0; t4 < 4; t4++) {
    int ocol = n0 + t4 * 16 + ln;
    float bb = 0.f;
    if (EPI == 1 || EPI == 2 || EPI == 3) bb = bias1[ocol];
#pragma unroll
    for (int r = 0; r < 4; r++) {
      int orow = m0 + wave * 16 + quad * 4 + r;
      float v = acc[t4][r];
      if (EPI == 1)      { v += bb; v = 1.f / (1.f + __expf(-v)); }
      else if (EPI == 2) { v += bb + resid[(long)orow * ldc + ocol]; }
      else if (EPI == 3) { v = fmaxf(v + bb, 0.f); }
      else if (EPI == 4) { v += bias2[(long)z * sB2z + (long)orow * ldc + ocol]; }
      long oidx = (long)z * sCz + (long)orow * ldc + ocol;
      if (EPI == 3) outH[oidx] = f2b(v);
      else          outF[oidx] = v;
    }
  }
}

// ---------------------------------------------------------------------------
// qkv prep: t[512][3072] f32 -> q(scaled)/k [16][512][64] bf16, v^T [16][64][512] bf16
// ---------------------------------------------------------------------------
__global__ __launch_bounds__(256) void qkv_prep(
    const float* __restrict__ t, unsigned short* __restrict__ qs,
    unsigned short* __restrict__ ks, unsigned short* __restrict__ vt) {
  int c = blockIdx.x * 256 + threadIdx.x;    // 0..3071
  int r = blockIdx.y;                        // 0..511
  float v = t[(long)r * 3072 + c];
  int h = c / 192, j = c - h * 192;
  if (j < 64)        qs[((long)h * 512 + r) * 64 + j] = f2b(v * 0.125f);
  else if (j < 128)  ks[((long)h * 512 + r) * 64 + (j - 64)] = f2b(v);
  else               vt[((long)h * 64 + (j - 128)) * 512 + r] = f2b(v);
}

// ---------------------------------------------------------------------------
// softmax over rows of S [16*512][512] f32 -> P bf16. wave per row.
// ---------------------------------------------------------------------------
__global__ __launch_bounds__(256) void softmax_rows(
    const float* __restrict__ S, unsigned short* __restrict__ P) {
  int row = blockIdx.x * 4 + (threadIdx.x >> 6);
  int lane = threadIdx.x & 63;
  const float* sr = S + (long)row * 512 + lane * 8;
  float4 a = *(const float4*)sr;
  float4 b = *(const float4*)(sr + 4);
  float m = fmaxf(fmaxf(fmaxf(a.x, a.y), fmaxf(a.z, a.w)),
                  fmaxf(fmaxf(b.x, b.y), fmaxf(b.z, b.w)));
#pragma unroll
  for (int k = 1; k < 64; k <<= 1) m = fmaxf(m, __shfl_xor(m, k));
  float e0 = __expf(a.x - m), e1 = __expf(a.y - m), e2 = __expf(a.z - m), e3 = __expf(a.w - m);
  float e4 = __expf(b.x - m), e5 = __expf(b.y - m), e6 = __expf(b.z - m), e7 = __expf(b.w - m);
  float s = e0 + e1 + e2 + e3 + e4 + e5 + e6 + e7;
#pragma unroll
  for (int k = 1; k < 64; k <<= 1) s += __shfl_xor(s, k);
  float inv = 1.f / s;
  uint4 o;
  o.x = pack2(e0 * inv, e1 * inv);
  o.y = pack2(e2 * inv, e3 * inv);
  o.z = pack2(e4 * inv, e5 * inv);
  o.w = pack2(e6 * inv, e7 * inv);
  *(uint4*)(P + (long)row * 512 + lane * 8) = o;
}

// ---------------------------------------------------------------------------
// gate apply: og = bf16(gate * o), 4 elems/thread
// ---------------------------------------------------------------------------
__global__ __launch_bounds__(256) void gate_apply(
    const float* __restrict__ gate, const float* __restrict__ o,
    unsigned short* __restrict__ og) {
  long i = ((long)blockIdx.x * 256 + threadIdx.x) * 4;
  float4 g = *(const float4*)(gate + i);
  float4 v = *(const float4*)(o + i);
  uint2 r;
  r.x = pack2(g.x * v.x, g.y * v.y);
  r.y = pack2(g.z * v.z, g.w * v.w);
  *(uint2*)(og + i) = r;
}

// ---------------------------------------------------------------------------
extern "C" void kernel_launch(void* const* d_in, const int* in_sizes, int n_in,
                              void* d_out, int out_size, void* d_ws, size_t ws_size,
                              hipStream_t stream) {
  const float* seq    = (const float*)d_in[0];
  const float* pw     = (const float*)d_in[1];
  // d_in[2] = mask (all true) — unused
  const float* ln1_g  = (const float*)d_in[3];
  const float* ln1_b  = (const float*)d_in[4];
  const float* proj_w = (const float*)d_in[5];
  const float* g_w    = (const float*)d_in[6];
  const float* g_b    = (const float*)d_in[7];
  const float* o_w    = (const float*)d_in[8];
  const float* o_b    = (const float*)d_in[9];
  const float* p2s_g  = (const float*)d_in[10];
  const float* p2s_b  = (const float*)d_in[11];
  const float* p2s_w  = (const float*)d_in[12];
  const float* mlp_g  = (const float*)d_in[13];
  const float* mlp_bb = (const float*)d_in[14];
  const float* w1     = (const float*)d_in[15];
  const float* b1     = (const float*)d_in[16];
  const float* w2     = (const float*)d_in[17];
  const float* b2     = (const float*)d_in[18];
  float* out = (float*)d_out;
  char* ws = (char*)d_ws;

  float* gw            = (float*)(ws + OFF_GW);
  float* Sb            = (float*)(ws + OFF_BIAS);
  unsigned short* P    = (unsigned short*)(ws + OFF_P);
  unsigned short* ybf  = (unsigned short*)(ws + OFF_Y);
  float* tbuf          = (float*)(ws + OFF_T);
  float* gatebuf       = (float*)(ws + OFF_GATE);
  unsigned short* qs   = (unsigned short*)(ws + OFF_QS);
  unsigned short* ks   = (unsigned short*)(ws + OFF_KS);
  unsigned short* vt   = (unsigned short*)(ws + OFF_VT);
  float* obuf          = (float*)(ws + OFF_O);
  unsigned short* og   = (unsigned short*)(ws + OFF_OG);
  float* sbuf          = (float*)(ws + OFF_S);
  unsigned short* hln  = (unsigned short*)(ws + OFF_HLN);
  unsigned short* h1   = (unsigned short*)(ws + OFF_H1);
  unsigned short* wproj= (unsigned short*)(ws + OFF_WPROJ);
  unsigned short* wg   = (unsigned short*)(ws + OFF_WG);
  unsigned short* wo   = (unsigned short*)(ws + OFF_WO);
  unsigned short* w1t  = (unsigned short*)(ws + OFF_W1);
  unsigned short* w2t  = (unsigned short*)(ws + OFF_W2);

  // setup + weight transposes (independent)
  p2s_setup<<<1, 256, 0, stream>>>(p2s_g, p2s_b, p2s_w, gw);
  transpose_cvt<<<dim3(48, 16), 256, 0, stream>>>(proj_w, wproj, 1024, 3072);
  transpose_cvt<<<dim3(16, 16), 256, 0, stream>>>(g_w, wg, 1024, 1024);
  transpose_cvt<<<dim3(16, 16), 256, 0, stream>>>(o_w, wo, 1024, 1024);
  transpose_cvt<<<dim3(64, 16), 256, 0, stream>>>(w1, w1t, 1024, 4096);
  transpose_cvt<<<dim3(16, 64), 256, 0, stream>>>(w2, w2t, 4096, 1024);

  // pairwise bias [16][512][512]
  p2s_main<<<16384, 256, 0, stream>>>(pw, gw, Sb);

  // sequence LN -> y bf16
  ln_rows<<<512, 256, 0, stream>>>(seq, ln1_g, ln1_b, ybf);

  // t = y @ proj_w   [512,3072]
  gemm_bt<0><<<dim3(48, 8, 1), 256, 0, stream>>>(ybf, wproj, nullptr, nullptr, nullptr,
                                                 tbuf, nullptr, 1024, 3072, 0, 0, 0, 0);
  // gate = sigmoid(y @ g_w + g_b)  [512,1024]
  gemm_bt<1><<<dim3(16, 8, 1), 256, 0, stream>>>(ybf, wg, g_b, nullptr, nullptr,
                                                 gatebuf, nullptr, 1024, 1024, 0, 0, 0, 0);
  // split/scale/transpose qkv
  qkv_prep<<<dim3(12, 512), 256, 0, stream>>>(tbuf, qs, ks, vt);

  // S[h] = q[h] @ k[h]^T + bias[h]   (in-place over bias buffer)
  gemm_bt<4><<<dim3(8, 8, 16), 256, 0, stream>>>(qs, ks, nullptr, Sb, nullptr,
                                                 Sb, nullptr, 64, 512,
                                                 32768, 32768, 262144, 262144);
  // softmax rows -> P bf16
  softmax_rows<<<2048, 256, 0, stream>>>(Sb, P);

  // o[h] = P[h] @ v[h]  -> o[512][1024] (col offset h*64)
  gemm_bt<0><<<dim3(1, 8, 16), 256, 0, stream>>>(P, vt, nullptr, nullptr, nullptr,
                                                 obuf, nullptr, 512, 1024,
                                                 262144, 32768, 64, 0);
  // og = bf16(gate * o)
  gate_apply<<<512, 256, 0, stream>>>(gatebuf, obuf, og);

  // s = seq + og @ o_w + o_b
  gemm_bt<2><<<dim3(16, 8, 1), 256, 0, stream>>>(og, wo, o_b, nullptr, seq,
                                                 sbuf, nullptr, 1024, 1024, 0, 0, 0, 0);
  // hln = LN(s)
  ln_rows<<<512, 256, 0, stream>>>(sbuf, mlp_g, mlp_bb, hln);

  // h1 = relu(hln @ w1 + b1) -> bf16 [512,4096]
  gemm_bt<3><<<dim3(64, 8, 1), 256, 0, stream>>>(hln, w1t, b1, nullptr, nullptr,
                                                 nullptr, h1, 1024, 4096, 0, 0, 0, 0);
  // out = s + h1 @ w2 + b2
  gemm_bt<2><<<dim3(16, 8, 1), 256, 0, stream>>>(h1, w2t, b2, nullptr, sbuf,
                                                 out, nullptr, 4096, 1024, 0, 0, 0, 0);
}

// Round 2
// 377.542 us; speedup vs baseline: 1.1284x; 1.1284x over previous
//
#include <hip/hip_runtime.h>

// ---------------------------------------------------------------------------
// SeqPairAttentionOutput on MI355X — round 2.
// B=1, L=512, D=1024, H=16, HW=64, PD=128.
// Changes vs r1: 64x128 GEMM w/ global_load_lds(16B); proj+gate merged with
// qkv/gate scatter epilogue; split-K for o_w & mlp2; PV epilogue applies gate;
// finalize fuses residual+bias(+LN); transposes merged into one launch.
// ---------------------------------------------------------------------------

typedef __attribute__((ext_vector_type(8))) short bfrag;   // 8 bf16 (4 VGPRs)
typedef __attribute__((ext_vector_type(4))) float f32x4;
typedef unsigned short ushort_t;
typedef unsigned int u32;

#define AS1 __attribute__((address_space(1)))
#define AS3 __attribute__((address_space(3)))

__device__ __forceinline__ void gll16(const void* g, void* l) {
  __builtin_amdgcn_global_load_lds((const AS1 u32*)g, (AS3 u32*)l, 16, 0, 0);
}

__device__ __forceinline__ unsigned short f2b(float x) {
  union { float f; unsigned u; } a; a.f = x;
  unsigned r = a.u + 0x7fffu + ((a.u >> 16) & 1u);   // RNE
  return (unsigned short)(r >> 16);
}
__device__ __forceinline__ unsigned pack2(float a, float b) {
  return (unsigned)f2b(a) | ((unsigned)f2b(b) << 16);
}

// ---------------------------------------------------------------------------
// workspace layout (bytes)
// ---------------------------------------------------------------------------
#define OFF_GW    ((size_t)0)                       // gw[16][128] + c1[16] + c2[16]
#define OFF_SB    ((size_t)65536)                   // bias/scores [16][512][512] f32 16MB
#define OFF_P     (OFF_SB   + (size_t)16777216)     // P bf16 [16][512][512] 8MB
#define OFF_Y     (OFF_P    + (size_t)8388608)      // y bf16 [512][1024] 1MB
#define OFF_QS    (OFF_Y    + (size_t)1048576)      // q bf16 [16][512][64] (scaled) 1MB
#define OFF_KS    (OFF_QS   + (size_t)1048576)      // k bf16 1MB
#define OFF_VT    (OFF_KS   + (size_t)1048576)      // v^T bf16 [16][64][512] 1MB
#define OFF_GATE  (OFF_VT   + (size_t)1048576)      // gate f32 [512][1024] 2MB
#define OFF_OG    (OFF_GATE + (size_t)2097152)      // gate*o bf16 [512][1024] 1MB
#define OFF_S     (OFF_OG   + (size_t)1048576)      // s f32 [512][1024] 2MB
#define OFF_HLN   (OFF_S    + (size_t)2097152)      // LN(s) bf16 1MB
#define OFF_H1    (OFF_HLN  + (size_t)1048576)      // h1 bf16 [512][4096] 4MB
#define OFF_PART  (OFF_H1   + (size_t)4194304)      // splitk partials [4][512][1024] f32 8MB
#define OFF_WPG   (OFF_PART + (size_t)8388608)      // [proj|g]^T bf16 [4096][1024] 8MB
#define OFF_WO    (OFF_WPG  + (size_t)8388608)      // o_w^T bf16 [1024][1024] 2MB
#define OFF_W1    (OFF_WO   + (size_t)2097152)      // w1^T bf16 [4096][1024] 8MB
#define OFF_W2    (OFF_W1   + (size_t)8388608)      // w2^T bf16 [1024][4096] 8MB

// ---------------------------------------------------------------------------
// p2s setup
// ---------------------------------------------------------------------------
__global__ __launch_bounds__(256) void p2s_setup(
    const float* __restrict__ g, const float* __restrict__ b,
    const float* __restrict__ w, float* __restrict__ gw) {
  int t = threadIdx.x;
  for (int i = t; i < 2048; i += 256) {
    int h = i >> 7, f = i & 127;
    gw[h * 128 + f] = g[f] * w[f * 16 + h];
  }
  if (t < 16) {
    float a = 0.f, c = 0.f;
    for (int f = 0; f < 128; f++) { a += g[f] * w[f * 16 + t]; c += b[f] * w[f * 16 + t]; }
    gw[2048 + t] = a;   // c1
    gw[2064 + t] = c;   // c2
  }
}

// ---------------------------------------------------------------------------
// p2s main: bias[h][q*512+k] = rs*(dot(x,gw_h) - mu*c1[h]) + c2[h]
// ---------------------------------------------------------------------------
__global__ __launch_bounds__(256) void p2s_main(
    const float* __restrict__ pw, const float* __restrict__ gw,
    float* __restrict__ biasOut) {
  __shared__ float xs[16 * 132];
  __shared__ float gwt[16 * 132];
  const int t = threadIdx.x;
  const long pair0 = (long)blockIdx.x * 16;
  const int p = t >> 4;
  const int h = t & 15;
  const int f0 = h * 8;

  float4 w0 = *(const float4*)&gw[p * 128 + f0];
  float4 w1 = *(const float4*)&gw[p * 128 + f0 + 4];
  *(float4*)&gwt[p * 132 + f0]     = w0;
  *(float4*)&gwt[p * 132 + f0 + 4] = w1;
  const float* src = pw + pair0 * 128 + (long)t * 8;
  float4 x0 = *(const float4*)src;
  float4 x1 = *(const float4*)(src + 4);
  *(float4*)&xs[p * 132 + f0]     = x0;
  *(float4*)&xs[p * 132 + f0 + 4] = x1;

  float s  = x0.x + x0.y + x0.z + x0.w + x1.x + x1.y + x1.z + x1.w;
  float sq = x0.x*x0.x + x0.y*x0.y + x0.z*x0.z + x0.w*x0.w
           + x1.x*x1.x + x1.y*x1.y + x1.z*x1.z + x1.w*x1.w;
#pragma unroll
  for (int m = 1; m < 16; m <<= 1) { s += __shfl_xor(s, m); sq += __shfl_xor(sq, m); }
  float mu  = s * (1.f / 128.f);
  float var = sq * (1.f / 128.f) - mu * mu;
  float rs  = rsqrtf(var + 1e-5f);

  __syncthreads();

  float acc = 0.f;
#pragma unroll 8
  for (int f = 0; f < 128; f += 4) {
    float4 xv = *(const float4*)&xs[p * 132 + f];
    float4 wv = *(const float4*)&gwt[h * 132 + f];
    acc += xv.x * wv.x + xv.y * wv.y + xv.z * wv.z + xv.w * wv.w;
  }
  float c1 = gw[2048 + h], c2 = gw[2064 + h];
  biasOut[(long)h * 262144 + pair0 + p] = rs * (acc - mu * c1) + c2;
}

// ---------------------------------------------------------------------------
// transpose + cvt: W[K][N] -> Wt[N][K] bf16, one merged launch
// ---------------------------------------------------------------------------
__device__ __forceinline__ void transp_tile(
    const float* __restrict__ W, ushort_t* __restrict__ Wt, int K, int N,
    int bx, int by, int tid) {
  __shared__ float tile[64][65];
  int n0 = bx * 64, k0 = by * 64;
  int tr = tid >> 4, tc = (tid & 15) * 4;
#pragma unroll
  for (int i = 0; i < 4; i++) {
    int r = tr + i * 16;
    float4 v = *(const float4*)&W[(long)(k0 + r) * N + n0 + tc];
    tile[r][tc] = v.x; tile[r][tc + 1] = v.y; tile[r][tc + 2] = v.z; tile[r][tc + 3] = v.w;
  }
  __syncthreads();
  int nr = tid >> 2, kk = (tid & 3) * 16;
  ushort_t* dst = Wt + (long)(n0 + nr) * K + k0 + kk;
  uint4 q;
  q.x = pack2(tile[kk + 0][nr], tile[kk + 1][nr]);
  q.y = pack2(tile[kk + 2][nr], tile[kk + 3][nr]);
  q.z = pack2(tile[kk + 4][nr], tile[kk + 5][nr]);
  q.w = pack2(tile[kk + 6][nr], tile[kk + 7][nr]);
  *(uint4*)dst = q;
  uint4 q2;
  q2.x = pack2(tile[kk + 8][nr],  tile[kk + 9][nr]);
  q2.y = pack2(tile[kk + 10][nr], tile[kk + 11][nr]);
  q2.z = pack2(tile[kk + 12][nr], tile[kk + 13][nr]);
  q2.w = pack2(tile[kk + 14][nr], tile[kk + 15][nr]);
  *(uint4*)(dst + 8) = q2;
}

// block ranges: [0,768) proj->wpg  [768,1024) g_w->wpg+3072*1024
//               [1024,1280) o_w->wo  [1280,2304) w1->w1t  [2304,3328) w2->w2t
__global__ __launch_bounds__(256) void transpose_all(
    const float* __restrict__ proj_w, const float* __restrict__ g_w,
    const float* __restrict__ o_w, const float* __restrict__ w1,
    const float* __restrict__ w2,
    ushort_t* __restrict__ wpg, ushort_t* __restrict__ wo,
    ushort_t* __restrict__ w1t, ushort_t* __restrict__ w2t) {
  int id = blockIdx.x, tid = threadIdx.x;
  if (id < 768)       transp_tile(proj_w, wpg, 1024, 3072, id % 48, id / 48, tid);
  else if (id < 1024) { int j = id - 768;  transp_tile(g_w, wpg + (long)3072 * 1024, 1024, 1024, j % 16, j / 16, tid); }
  else if (id < 1280) { int j = id - 1024; transp_tile(o_w, wo, 1024, 1024, j % 16, j / 16, tid); }
  else if (id < 2304) { int j = id - 1280; transp_tile(w1, w1t, 1024, 4096, j % 64, j / 64, tid); }
  else                { int j = id - 2304; transp_tile(w2, w2t, 4096, 1024, j % 16, j / 16, tid); }
}

// ---------------------------------------------------------------------------
// row LayerNorm (C=1024) -> bf16
// ---------------------------------------------------------------------------
__global__ __launch_bounds__(256) void ln_rows(
    const float* __restrict__ x, const float* __restrict__ g,
    const float* __restrict__ b, ushort_t* __restrict__ out) {
  __shared__ float ps[8];
  int row = blockIdx.x, t = threadIdx.x;
  float4 v = *(const float4*)(x + (long)row * 1024 + t * 4);
  float s  = v.x + v.y + v.z + v.w;
  float sq = v.x*v.x + v.y*v.y + v.z*v.z + v.w*v.w;
#pragma unroll
  for (int k = 1; k < 64; k <<= 1) { s += __shfl_xor(s, k); sq += __shfl_xor(sq, k); }
  if ((t & 63) == 0) { ps[t >> 6] = s; ps[4 + (t >> 6)] = sq; }
  __syncthreads();
  s  = ps[0] + ps[1] + ps[2] + ps[3];
  sq = ps[4] + ps[5] + ps[6] + ps[7];
  float mu = s * (1.f / 1024.f);
  float rs = rsqrtf(sq * (1.f / 1024.f) - mu * mu + 1e-5f);
  float4 gv = *(const float4*)(g + t * 4);
  float4 bv = *(const float4*)(b + t * 4);
  uint2 o;
  o.x = pack2((v.x - mu) * rs * gv.x + bv.x, (v.y - mu) * rs * gv.y + bv.y);
  o.y = pack2((v.z - mu) * rs * gv.z + bv.z, (v.w - mu) * rs * gv.w + bv.w);
  *(uint2*)(out + (long)row * 1024 + t * 4) = o;
}

// ---------------------------------------------------------------------------
// 64(M) x 128(N) MFMA GEMM, global_load_lds staging, Bt layout [N][K].
// 4 waves in 2x2; each wave 32x64 (2 a-frags x 4 b-frags, 8 MFMA / K-32).
// EPI 0: splitk partial fp32 -> outF + z*524288
// EPI 3: relu(acc + bias1[ocol]) -> outH bf16 (ldc)
// EPI 6: proj+gate scatter (qs/ks/vt bf16, sigmoid gate fp32)
// ---------------------------------------------------------------------------
template <int EPI>
__global__ __launch_bounds__(256) void gemm128(
    const ushort_t* __restrict__ A, const ushort_t* __restrict__ Bt,
    int lda, int ldb, int Ksplit,
    const float* __restrict__ bias1,
    float* __restrict__ outF, ushort_t* __restrict__ outH, int ldc,
    ushort_t* __restrict__ qs, ushort_t* __restrict__ ks,
    ushort_t* __restrict__ vt, float* __restrict__ gatebuf) {
  __shared__ ushort_t As[64 * 32];    // 4 KB
  __shared__ ushort_t Bs[128 * 32];   // 8 KB
  const int tid = threadIdx.x;
  const int w = tid >> 6, lane = tid & 63;
  const int ln = lane & 15, quad = lane >> 4;
  const int wm = w >> 1, wn = w & 1;
  const int m0 = blockIdx.y * 64, n0 = blockIdx.x * 128;
  const int z = blockIdx.z;
  const int Koff = (EPI == 0) ? z * Ksplit : 0;

  const ushort_t* ga  = A  + (long)(m0 + (tid >> 2)) * lda + Koff + (tid & 3) * 8;
  const ushort_t* gb0 = Bt + (long)(n0 + (tid >> 2)) * ldb + Koff + (tid & 3) * 8;
  const ushort_t* gb1 = gb0 + (long)64 * ldb;
  unsigned wofs = __builtin_amdgcn_readfirstlane(w * 1024);
  char* lA  = (char*)As + wofs;
  char* lB0 = (char*)Bs + wofs;
  char* lB1 = (char*)Bs + 4096 + wofs;

  f32x4 acc[2][4];
#pragma unroll
  for (int i = 0; i < 2; i++)
#pragma unroll
    for (int j = 0; j < 4; j++) acc[i][j] = (f32x4){0.f, 0.f, 0.f, 0.f};

  for (int k0 = 0; k0 < Ksplit; k0 += 32) {
    gll16(ga + k0, lA);
    gll16(gb0 + k0, lB0);
    gll16(gb1 + k0, lB1);
    __syncthreads();
    bfrag a0 = *(const bfrag*)&As[(wm * 32 + ln) * 32 + quad * 8];
    bfrag a1 = *(const bfrag*)&As[(wm * 32 + 16 + ln) * 32 + quad * 8];
#pragma unroll
    for (int bn = 0; bn < 4; bn++) {
      bfrag b = *(const bfrag*)&Bs[(wn * 64 + bn * 16 + ln) * 32 + quad * 8];
      acc[0][bn] = __builtin_amdgcn_mfma_f32_16x16x32_bf16(a0, b, acc[0][bn], 0, 0, 0);
      acc[1][bn] = __builtin_amdgcn_mfma_f32_16x16x32_bf16(a1, b, acc[1][bn], 0, 0, 0);
    }
    __syncthreads();
  }

#pragma unroll
  for (int am = 0; am < 2; am++) {
#pragma unroll
    for (int bn = 0; bn < 4; bn++) {
      int ocol = n0 + wn * 64 + bn * 16 + ln;
#pragma unroll
      for (int r = 0; r < 4; r++) {
        int orow = m0 + wm * 32 + am * 16 + quad * 4 + r;
        float v = acc[am][bn][r];
        if (EPI == 0) {
          outF[(long)z * 524288 + (long)orow * ldc + ocol] = v;
        } else if (EPI == 3) {
          v = fmaxf(v + bias1[ocol], 0.f);
          outH[(long)orow * ldc + ocol] = f2b(v);
        } else if (EPI == 6) {
          if (ocol < 3072) {
            int h = ocol / 192, j = ocol - h * 192;   // 16-aligned segments: wave-uniform per bn
            if (j < 64)       qs[((long)h * 512 + orow) * 64 + j] = f2b(v * 0.125f);
            else if (j < 128) ks[((long)h * 512 + orow) * 64 + (j - 64)] = f2b(v);
            else              vt[((long)h * 64 + (j - 128)) * 512 + orow] = f2b(v);
          } else {
            int gcol = ocol - 3072;
            float gv = v + bias1[gcol];
            gatebuf[(long)orow * 1024 + gcol] = 1.f / (1.f + __expf(-gv));
          }
        }
      }
    }
  }
}

// ---------------------------------------------------------------------------
// 64x64 MFMA GEMM (register-staged) for scores & PV.
// EPI 4: acc + bias2[z][m][n](ldb2)       -> outF
// EPI 5: acc * bias2[z][m][n](ldb2) gate  -> outH bf16
// ---------------------------------------------------------------------------
template <int EPI>
__global__ __launch_bounds__(256) void gemm_bt(
    const ushort_t* __restrict__ A, const ushort_t* __restrict__ Bt,
    const float* __restrict__ bias2, int ldb2,
    float* __restrict__ outF, ushort_t* __restrict__ outH,
    int K, int ldc, long sAz, long sBz, long sCz, long sB2z) {
  __shared__ ushort_t As[64 * 40];
  __shared__ ushort_t Bs[64 * 40];
  const int tid = threadIdx.x;
  const int wave = tid >> 6, lane = tid & 63;
  const int srow = tid >> 2;
  const int skcol = (tid & 3) * 8;
  const int m0 = blockIdx.y * 64, n0 = blockIdx.x * 64;
  const int z = blockIdx.z;
  const ushort_t* Az = A + (long)z * sAz + (long)m0 * K;
  const ushort_t* Bz = Bt + (long)z * sBz + (long)n0 * K;
  const int ln = lane & 15, quad = lane >> 4;

  f32x4 acc[4];
#pragma unroll
  for (int i = 0; i < 4; i++) acc[i] = (f32x4){0.f, 0.f, 0.f, 0.f};

  for (int k0 = 0; k0 < K; k0 += 32) {
    uint4 av = *(const uint4*)(Az + (long)srow * K + k0 + skcol);
    uint4 bv = *(const uint4*)(Bz + (long)srow * K + k0 + skcol);
    __syncthreads();
    *(uint4*)&As[srow * 40 + skcol] = av;
    *(uint4*)&Bs[srow * 40 + skcol] = bv;
    __syncthreads();
    bfrag a = *(const bfrag*)&As[(wave * 16 + ln) * 40 + quad * 8];
#pragma unroll
    for (int t4 = 0; t4 < 4; t4++) {
      bfrag b = *(const bfrag*)&Bs[(t4 * 16 + ln) * 40 + quad * 8];
      acc[t4] = __builtin_amdgcn_mfma_f32_16x16x32_bf16(a, b, acc[t4], 0, 0, 0);
    }
  }

#pragma unroll
  for (int t4 = 0; t4 < 4; t4++) {
    int ocol = n0 + t4 * 16 + ln;
#pragma unroll
    for (int r = 0; r < 4; r++) {
      int orow = m0 + wave * 16 + quad * 4 + r;
      float v = acc[t4][r];
      long oidx = (long)z * sCz + (long)orow * ldc + ocol;
      if (EPI == 4) {
        v += bias2[(long)z * sB2z + (long)orow * ldb2 + ocol];
        outF[oidx] = v;
      } else { // EPI 5
        v *= bias2[(long)z * sB2z + (long)orow * ldb2 + ocol];
        outH[oidx] = f2b(v);
      }
    }
  }
}

// ---------------------------------------------------------------------------
// softmax over rows of S [16*512][512] f32 -> P bf16. wave per row.
// ---------------------------------------------------------------------------
__global__ __launch_bounds__(256) void softmax_rows(
    const float* __restrict__ S, ushort_t* __restrict__ P) {
  int row = blockIdx.x * 4 + (threadIdx.x >> 6);
  int lane = threadIdx.x & 63;
  const float* sr = S + (long)row * 512 + lane * 8;
  float4 a = *(const float4*)sr;
  float4 b = *(const float4*)(sr + 4);
  float m = fmaxf(fmaxf(fmaxf(a.x, a.y), fmaxf(a.z, a.w)),
                  fmaxf(fmaxf(b.x, b.y), fmaxf(b.z, b.w)));
#pragma unroll
  for (int k = 1; k < 64; k <<= 1) m = fmaxf(m, __shfl_xor(m, k));
  float e0 = __expf(a.x - m), e1 = __expf(a.y - m), e2 = __expf(a.z - m), e3 = __expf(a.w - m);
  float e4 = __expf(b.x - m), e5 = __expf(b.y - m), e6 = __expf(b.z - m), e7 = __expf(b.w - m);
  float s = e0 + e1 + e2 + e3 + e4 + e5 + e6 + e7;
#pragma unroll
  for (int k = 1; k < 64; k <<= 1) s += __shfl_xor(s, k);
  float inv = 1.f / s;
  uint4 o;
  o.x = pack2(e0 * inv, e1 * inv);
  o.y = pack2(e2 * inv, e3 * inv);
  o.z = pack2(e4 * inv, e5 * inv);
  o.w = pack2(e6 * inv, e7 * inv);
  *(uint4*)(P + (long)row * 512 + lane * 8) = o;
}

// ---------------------------------------------------------------------------
// finalize: acc = resid + sum_z part[z] + bias; DO_LN: store acc fp32 + LN->bf16
// else store acc fp32 to f_out. block per row (512 blocks).
// ---------------------------------------------------------------------------
template <int DO_LN>
__global__ __launch_bounds__(256) void finalize_row(
    const float* __restrict__ resid, const float* __restrict__ part,
    const float* __restrict__ bias,
    const float* __restrict__ g, const float* __restrict__ b,
    float* __restrict__ s_out, ushort_t* __restrict__ h_out) {
  __shared__ float ps[8];
  int row = blockIdx.x, t = threadIdx.x;
  long base = (long)row * 1024 + t * 4;
  float4 v = *(const float4*)(resid + base);
#pragma unroll
  for (int zz = 0; zz < 4; zz++) {
    float4 p = *(const float4*)(part + (long)zz * 524288 + base);
    v.x += p.x; v.y += p.y; v.z += p.z; v.w += p.w;
  }
  float4 bv = *(const float4*)(bias + t * 4);
  v.x += bv.x; v.y += bv.y; v.z += bv.z; v.w += bv.w;
  *(float4*)(s_out + base) = v;
  if (DO_LN) {
    float s  = v.x + v.y + v.z + v.w;
    float sq = v.x*v.x + v.y*v.y + v.z*v.z + v.w*v.w;
#pragma unroll
    for (int k = 1; k < 64; k <<= 1) { s += __shfl_xor(s, k); sq += __shfl_xor(sq, k); }
    if ((t & 63) == 0) { ps[t >> 6] = s; ps[4 + (t >> 6)] = sq; }
    __syncthreads();
    s  = ps[0] + ps[1] + ps[2] + ps[3];
    sq = ps[4] + ps[5] + ps[6] + ps[7];
    float mu = s * (1.f / 1024.f);
    float rs = rsqrtf(sq * (1.f / 1024.f) - mu * mu + 1e-5f);
    float4 gv = *(const float4*)(g + t * 4);
    float4 bb = *(const float4*)(b + t * 4);
    uint2 o;
    o.x = pack2((v.x - mu) * rs * gv.x + bb.x, (v.y - mu) * rs * gv.y + bb.y);
    o.y = pack2((v.z - mu) * rs * gv.z + bb.z, (v.w - mu) * rs * gv.w + bb.w);
    *(uint2*)(h_out + base) = o;
  }
}

// ---------------------------------------------------------------------------
extern "C" void kernel_launch(void* const* d_in, const int* in_sizes, int n_in,
                              void* d_out, int out_size, void* d_ws, size_t ws_size,
                              hipStream_t stream) {
  const float* seq    = (const float*)d_in[0];
  const float* pw     = (const float*)d_in[1];
  const float* ln1_g  = (const float*)d_in[3];
  const float* ln1_b  = (const float*)d_in[4];
  const float* proj_w = (const float*)d_in[5];
  const float* g_w    = (const float*)d_in[6];
  const float* g_b    = (const float*)d_in[7];
  const float* o_w    = (const float*)d_in[8];
  const float* o_b    = (const float*)d_in[9];
  const float* p2s_g  = (const float*)d_in[10];
  const float* p2s_b  = (const float*)d_in[11];
  const float* p2s_w  = (const float*)d_in[12];
  const float* mlp_g  = (const float*)d_in[13];
  const float* mlp_bb = (const float*)d_in[14];
  const float* w1     = (const float*)d_in[15];
  const float* b1     = (const float*)d_in[16];
  const float* w2     = (const float*)d_in[17];
  const float* b2     = (const float*)d_in[18];
  float* out = (float*)d_out;
  char* ws = (char*)d_ws;

  float* gw          = (float*)(ws + OFF_GW);
  float* Sb          = (float*)(ws + OFF_SB);
  ushort_t* P        = (ushort_t*)(ws + OFF_P);
  ushort_t* ybf      = (ushort_t*)(ws + OFF_Y);
  ushort_t* qs       = (ushort_t*)(ws + OFF_QS);
  ushort_t* ks       = (ushort_t*)(ws + OFF_KS);
  ushort_t* vt       = (ushort_t*)(ws + OFF_VT);
  float* gatebuf     = (float*)(ws + OFF_GATE);
  ushort_t* og       = (ushort_t*)(ws + OFF_OG);
  float* sbuf        = (float*)(ws + OFF_S);
  ushort_t* hln      = (ushort_t*)(ws + OFF_HLN);
  ushort_t* h1       = (ushort_t*)(ws + OFF_H1);
  float* part        = (float*)(ws + OFF_PART);
  ushort_t* wpg      = (ushort_t*)(ws + OFF_WPG);
  ushort_t* wo       = (ushort_t*)(ws + OFF_WO);
  ushort_t* w1t      = (ushort_t*)(ws + OFF_W1);
  ushort_t* w2t      = (ushort_t*)(ws + OFF_W2);

  p2s_setup<<<1, 256, 0, stream>>>(p2s_g, p2s_b, p2s_w, gw);
  transpose_all<<<3328, 256, 0, stream>>>(proj_w, g_w, o_w, w1, w2, wpg, wo, w1t, w2t);
  p2s_main<<<16384, 256, 0, stream>>>(pw, gw, Sb);
  ln_rows<<<512, 256, 0, stream>>>(seq, ln1_g, ln1_b, ybf);

  // merged proj+gate: y[512,1024] @ wpg^T[4096,1024] -> qkv scatter + gate
  gemm128<6><<<dim3(32, 8, 1), 256, 0, stream>>>(ybf, wpg, 1024, 1024, 1024,
                                                 g_b, nullptr, nullptr, 0,
                                                 qs, ks, vt, gatebuf);
  // S[h] = q[h] @ k[h]^T + bias[h]  (in place over Sb)
  gemm_bt<4><<<dim3(8, 8, 16), 256, 0, stream>>>(qs, ks, Sb, 512, Sb, nullptr,
                                                 64, 512, 32768, 32768, 262144, 262144);
  softmax_rows<<<2048, 256, 0, stream>>>(Sb, P);
  // og[q][h*64+c] = gate * (P[h] @ v[h])  bf16
  gemm_bt<5><<<dim3(1, 8, 16), 256, 0, stream>>>(P, vt, gatebuf, 1024, nullptr, og,
                                                 512, 1024, 262144, 32768, 64, 64);
  // o_w GEMM split-K=4 (K=1024 -> 256 each)
  gemm128<0><<<dim3(8, 8, 4), 256, 0, stream>>>(og, wo, 1024, 1024, 256,
                                                nullptr, part, nullptr, 1024,
                                                nullptr, nullptr, nullptr, nullptr);
  // s = seq + sum(part) + o_b ; hln = LN(s)
  finalize_row<1><<<512, 256, 0, stream>>>(seq, part, o_b, mlp_g, mlp_bb, sbuf, hln);
  // h1 = relu(hln @ w1 + b1) bf16
  gemm128<3><<<dim3(32, 8, 1), 256, 0, stream>>>(hln, w1t, 1024, 1024, 1024,
                                                 b1, nullptr, h1, 4096,
                                                 nullptr, nullptr, nullptr, nullptr);
  // mlp2 split-K=4 (K=4096 -> 1024 each)
  gemm128<0><<<dim3(8, 8, 4), 256, 0, stream>>>(h1, w2t, 4096, 4096, 1024,
                                                nullptr, part, nullptr, 1024,
                                                nullptr, nullptr, nullptr, nullptr);
  // out = sbuf + sum(part) + b2
  finalize_row<0><<<512, 256, 0, stream>>>(sbuf, part, b2, nullptr, nullptr, out, nullptr);
}